// Round 4
// baseline (196.031 us; speedup 1.0000x reference)
//
#include <hip/hip_runtime.h>
#include <hip/hip_bf16.h>

// Problem: B=4096, L=50, D=64, E=128, CAT=384, U=256, V=100000
// Dtypes per reference: ALL float tensors fp32, ids/mask int32, out fp32 [B,E].
//
// Factored algebra: h = relu(q·W_q + k·W_k + (q*k)·W_qk + b_hide)
//   qv[u] = q·W_q[:,u] + b_hide[u]   (fp32 VALU, split-K halves, coalesced W_q)
//   GEMM per b: swapped operands C[u,l]: A-op = W fragments (global, coalesced),
//   B-op = [K | K*q] rows (LDS).  C layout: col(lane&15)=l, row(quad*4+reg)=u.
// scores = (relu(C+qv)·W_out + b_out) * mask ; out[b] = scores · K   (fp32)
//
// V5 vs V4 (75.7us/dispatch): V4 fixed W coalescing (2x). Counters still show
// all pipes <31% (MFMA 18, VALU 30, DS ~23) -> latency-bound on the per-b
// serial chain (id->gather ~900cy -> 6 barrier-separated phases). V5 pipelines
// ACROSS b's: each block owns NB=4 consecutive b's; gather(b+1) issues into
// regs before qv/MFMA(b) and lands in LDS at the iteration tail (after last
// Kb reader). ids prefetched one more iteration ahead (avoids ptr-chase stall).
// All compute phases / LDS layouts / rounding points verbatim V4.

#define L_SEQ 50
#define LP    64
#define D_EMB 64
#define E_DIM 128
#define U_DIM 256
#define CATK  384
#define V_SZ  100000
#define KSTR  136   // LDS row stride (bf16): 272B = 17*16B -> bank rotation by 4/row
#define NB    4     // b's per block; grid = 4096/NB = 1024

typedef __bf16 bf16x2 __attribute__((ext_vector_type(2)));
typedef __bf16 bf16x4 __attribute__((ext_vector_type(4)));
typedef __bf16 bf16x8 __attribute__((ext_vector_type(8)));
typedef float  f32x4  __attribute__((ext_vector_type(4)));

// module-owned weight caches (written by prep each launch):
// g_W3: W_k/W_qk slice in MFMA fragment order: [s=8][ut=16][lane=64][j=8] bf16 =128KB
// g_Wq_c: W_q slice c-major (== W_hide layout, rows 0..127), bf16 = 64KB
__device__ __bf16 g_W3[65536];
__device__ __bf16 g_Wq_c[128 * 256];

// ---- prep: build g_Wq_c (linear copy+cast) and g_W3 (fragment shuffle) ----
__global__ __launch_bounds__(256) void prep_kernel(const float* __restrict__ W_hide) {
  const int bid = blockIdx.x, t = threadIdx.x;
  if (bid < 32) {
    const int base = bid * 1024;
#pragma unroll
    for (int i = 0; i < 4; ++i) {
      int idx = base + i * 256 + t;
      g_Wq_c[idx] = (__bf16)W_hide[idx];   // coalesced read & write
    }
  } else {
    const int o = (bid - 32) * 256 + t;          // 0..8191
    const int s = o >> 10, ut = (o >> 6) & 15, lane = o & 63;
    const int quad = lane >> 4, m = lane & 15;
    const int u = ut * 16 + m;
    const int c0 = 128 + s * 32 + quad * 8;
    bf16x8 v;
#pragma unroll
    for (int j = 0; j < 8; ++j)
      v[j] = (__bf16)W_hide[(c0 + j) * 256 + u];  // scattered 4B reads (tiny kernel)
    *(bf16x8*)&g_W3[o * 8] = v;                   // coalesced 16B write
  }
}

// ---- main: one block (4 waves, 256 threads) per NB consecutive b ----
__global__ __launch_bounds__(256) void din_main_kernel(
    const int* __restrict__ qid_item, const int* __restrict__ qid_cate,
    const int* __restrict__ seq_item, const int* __restrict__ seq_cate,
    const int* __restrict__ mask,
    const float* __restrict__ emb_item,
    const float* __restrict__ emb_cate,
    const float* __restrict__ b_hide,  // [256]
    const float* __restrict__ W_out,   // [256]
    const float* __restrict__ b_out,   // [1]
    float* __restrict__ out) {
  __shared__ alignas(16) __bf16 Kb[LP * KSTR];   // bf16(K)
  __shared__ alignas(16) __bf16 A2[LP * KSTR];   // bf16(K*q)
  __shared__ alignas(16) float qrowf[E_DIM];     // fp32 q
  __shared__ alignas(16) float qv2[2][U_DIM];    // split-K partials of b_hide+q·W_q
  __shared__ float mask_f[LP];
  __shared__ float scpart[4][LP];                // per-wave u-partial scores
  __shared__ float scores_s[LP];
  __shared__ float outp[4][E_DIM];               // per-wave l-partial outputs

  const int b0 = blockIdx.x * NB;
  const int t = threadIdx.x;
  const int r = t >> 2, q4 = t & 3;
  const int col0 = q4 * 32;   // this thread's 32 columns of [item|cate]
  const int wave = t >> 6, lane = t & 63;
  const int m = lane & 15, quad = lane >> 4;
  const int rr = (r < L_SEQ) ? r : 0;   // clamped row for id loads

  // ---- prefetch state (next-b): ids, K rows, q slice, mask ----
  int sid, qidv = 0, mkv;
  float4 kvp[8];
  float4 qrp = make_float4(0.f, 0.f, 0.f, 0.f);

  // prologue: ids(b0) -> gather(b0) -> ids(b0+1) -> stage(b0)
  sid = (q4 < 2 ? seq_item : seq_cate)[b0 * L_SEQ + rr];
  if (t < 32) qidv = (t < 16 ? qid_item : qid_cate)[b0];
  mkv = (t < L_SEQ) ? mask[b0 * L_SEQ + t] : 0;

  if (r < L_SEQ) {
    int id = sid; if ((unsigned)id >= (unsigned)V_SZ) id = 0;
    const float4* s4 = (const float4*)(((q4 < 2) ? emb_item : emb_cate)
                                       + (size_t)id * D_EMB + (q4 & 1) * 32);
#pragma unroll
    for (int i2 = 0; i2 < 8; ++i2) kvp[i2] = s4[i2];
  } else {
#pragma unroll
    for (int i2 = 0; i2 < 8; ++i2) kvp[i2] = make_float4(0.f, 0.f, 0.f, 0.f);
  }
  if (t < 32) {
    int id = qidv; if ((unsigned)id >= (unsigned)V_SZ) id = 0;
    qrp = *(const float4*)(((t < 16) ? emb_item : emb_cate)
                           + (size_t)id * D_EMB + (t & 15) * 4);
  }
  int mk_cur = mkv;
  if (NB > 1) {   // ids(b0+1) one iteration ahead
    sid = (q4 < 2 ? seq_item : seq_cate)[(b0 + 1) * L_SEQ + rr];
    if (t < 32) qidv = (t < 16 ? qid_item : qid_cate)[b0 + 1];
    mkv = (t < L_SEQ) ? mask[(b0 + 1) * L_SEQ + t] : 0;
  }
  // H1(b0): Kb, qrowf, mask_f
#pragma unroll
  for (int i2 = 0; i2 < 8; ++i2) {
    bf16x4 h4 = {(__bf16)kvp[i2].x, (__bf16)kvp[i2].y,
                 (__bf16)kvp[i2].z, (__bf16)kvp[i2].w};
    *(bf16x4*)&Kb[r * KSTR + col0 + i2 * 4] = h4;
  }
  if (t < 32) *(float4*)&qrowf[(t < 16 ? 0 : 64) + (t & 15) * 4] = qrp;
  if (t < LP) mask_f[t] = (t < L_SEQ && mk_cur != 0) ? 1.0f : 0.0f;
  __syncthreads();
  // H2(b0): A2 = bf16(K*q), single rounding from fp32 regs
#pragma unroll
  for (int i2 = 0; i2 < 8; ++i2) {
    const float* qp = &qrowf[col0 + i2 * 4];
    bf16x4 h4 = {(__bf16)(kvp[i2].x * qp[0]), (__bf16)(kvp[i2].y * qp[1]),
                 (__bf16)(kvp[i2].z * qp[2]), (__bf16)(kvp[i2].w * qp[3])};
    *(bf16x4*)&A2[r * KSTR + col0 + i2 * 4] = h4;
  }
  __syncthreads();

  for (int i = 0; i < NB; ++i) {
    const int b = b0 + i;
    const bool more = (i + 1 < NB);
    float4 kq[8];
    float4 qq = make_float4(0.f, 0.f, 0.f, 0.f);
    int mq = 0;

    // ---- A: issue gather(b+1) into regs; then ids(b+2) ----
    if (more) {
      if (r < L_SEQ) {
        int id = sid; if ((unsigned)id >= (unsigned)V_SZ) id = 0;
        const float4* s4 = (const float4*)(((q4 < 2) ? emb_item : emb_cate)
                                           + (size_t)id * D_EMB + (q4 & 1) * 32);
#pragma unroll
        for (int i2 = 0; i2 < 8; ++i2) kq[i2] = s4[i2];
      } else {
#pragma unroll
        for (int i2 = 0; i2 < 8; ++i2) kq[i2] = make_float4(0.f, 0.f, 0.f, 0.f);
      }
      if (t < 32) {
        int id = qidv; if ((unsigned)id >= (unsigned)V_SZ) id = 0;
        qq = *(const float4*)(((t < 16) ? emb_item : emb_cate)
                              + (size_t)id * D_EMB + (t & 15) * 4);
      }
      mq = mkv;
      if (i + 2 < NB) {
        sid = (q4 < 2 ? seq_item : seq_cate)[(b + 2) * L_SEQ + rr];
        if (t < 32) qidv = (t < 16 ? qid_item : qid_cate)[b + 2];
        mkv = (t < L_SEQ) ? mask[(b + 2) * L_SEQ + t] : 0;
      }
    }

    // ---- B: qv2[ch][u] partials, coalesced c-major W_q reads ----
    {
      const int ch = t >> 7;               // c-half: [0,64) or [64,128)
      const int u0 = (t & 127) * 2;        // this thread owns u0, u0+1
      float a0 = ch ? 0.f : b_hide[u0];
      float a1 = ch ? 0.f : b_hide[u0 + 1];
      const __bf16* wp = &g_Wq_c[(ch * 64) * 256 + u0];
      const float* qp = &qrowf[ch * 64];
#pragma unroll 16
      for (int cc = 0; cc < 64; ++cc) {
        bf16x2 w2 = *(const bf16x2*)(wp + cc * 256);  // lane-consecutive 4B
        float qc = qp[cc];                            // wave-uniform LDS broadcast
        a0 += qc * (float)w2[0];
        a1 += qc * (float)w2[1];
      }
      qv2[ch][u0] = a0;
      qv2[ch][u0 + 1] = a1;
    }

    // ---- C: swapped MFMA. M=u (64/wave, 4 tiles), N=l (64, 4 tiles), K=256 ----
    f32x4 acc[4][4];
#pragma unroll
    for (int mt = 0; mt < 4; ++mt)
#pragma unroll
      for (int nt = 0; nt < 4; ++nt) acc[mt][nt] = (f32x4){0.f, 0.f, 0.f, 0.f};

#pragma unroll
    for (int s = 0; s < 8; ++s) {
      const __bf16* Bb = (s < 4) ? Kb : A2;
      const int klocal = (s & 3) * 32 + quad * 8;
      bf16x8 wfr[4], kfr[4];
#pragma unroll
      for (int mt = 0; mt < 4; ++mt) {
        const int o = s * 1024 + (wave * 4 + mt) * 64 + lane;   // fragment-ordered
        wfr[mt] = *(const bf16x8*)&g_W3[o * 8];
      }
#pragma unroll
      for (int nt = 0; nt < 4; ++nt)
        kfr[nt] = *(const bf16x8*)&Bb[(nt * 16 + m) * KSTR + klocal];
#pragma unroll
      for (int mt = 0; mt < 4; ++mt)
#pragma unroll
        for (int nt = 0; nt < 4; ++nt)
          acc[mt][nt] = __builtin_amdgcn_mfma_f32_16x16x32_bf16(
              wfr[mt], kfr[nt], acc[mt][nt], 0, 0, 0);
    }
    __syncthreads();   // qv2 ready; all Kb/A2 MFMA reads done

    // ---- D: epilogue: part[nt] = sum_u relu(C+qv[u])*W_out[u] ----
    float qv4[4][4], wo4[4][4];
#pragma unroll
    for (int mt = 0; mt < 4; ++mt) {
      const int u0 = wave * 64 + mt * 16 + quad * 4;
      f32x4 qa = *(const f32x4*)&qv2[0][u0];
      f32x4 qb = *(const f32x4*)&qv2[1][u0];
      float4 ww = *(const float4*)&W_out[u0];
      qv4[mt][0] = qa[0] + qb[0]; qv4[mt][1] = qa[1] + qb[1];
      qv4[mt][2] = qa[2] + qb[2]; qv4[mt][3] = qa[3] + qb[3];
      wo4[mt][0] = ww.x;  wo4[mt][1] = ww.y;  wo4[mt][2] = ww.z;  wo4[mt][3] = ww.w;
    }
    float part[4];
#pragma unroll
    for (int nt = 0; nt < 4; ++nt) {
      float sum = 0.f;
#pragma unroll
      for (int mt = 0; mt < 4; ++mt)
#pragma unroll
        for (int rg = 0; rg < 4; ++rg) {
          float h = acc[mt][nt][rg] + qv4[mt][rg];
          h = fmaxf(h, 0.f);
          sum += h * wo4[mt][rg];
        }
      part[nt] = sum;
    }
#pragma unroll
    for (int nt = 0; nt < 4; ++nt) {   // reduce over 4 quads
      part[nt] += __shfl_xor(part[nt], 16, 64);
      part[nt] += __shfl_xor(part[nt], 32, 64);
    }
    if (lane < 16) {
#pragma unroll
      for (int nt = 0; nt < 4; ++nt)
        scpart[wave][nt * 16 + lane] = part[nt];   // l = nt*16+lane
    }
    __syncthreads();

    // ---- E: scores ----
    if (t < LP) {
      float s = scpart[0][t] + scpart[1][t] + scpart[2][t] + scpart[3][t]
              + b_out[0];
      scores_s[t] = s * mask_f[t];
    }
    __syncthreads();

    // ---- F: out partials (last Kb reader) ----
    {
      const int e2 = lane * 2;
      float o0 = 0.f, o1 = 0.f;
#pragma unroll
      for (int i2 = 0; i2 < 16; ++i2) {
        const int l = wave * 16 + i2;
        const float sc = scores_s[l];
        bf16x2 kk = *(const bf16x2*)&Kb[l * KSTR + e2];
        o0 += sc * (float)kk[0];
        o1 += sc * (float)kk[1];
      }
      outp[wave][e2]     = o0;
      outp[wave][e2 + 1] = o1;
    }
    __syncthreads();

    // ---- G: final out write;  H1(b+1): stage Kb/qrowf/mask from regs ----
    if (t < E_DIM) {
      float o = outp[0][t] + outp[1][t] + outp[2][t] + outp[3][t];
      out[(size_t)b * E_DIM + t] = o;
    }
    if (more) {
#pragma unroll
      for (int i2 = 0; i2 < 8; ++i2) {
        bf16x4 h4 = {(__bf16)kq[i2].x, (__bf16)kq[i2].y,
                     (__bf16)kq[i2].z, (__bf16)kq[i2].w};
        *(bf16x4*)&Kb[r * KSTR + col0 + i2 * 4] = h4;
      }
      if (t < 32) *(float4*)&qrowf[(t < 16 ? 0 : 64) + (t & 15) * 4] = qq;
      if (t < LP) mask_f[t] = (t < L_SEQ && mq != 0) ? 1.0f : 0.0f;
      __syncthreads();
      // H2(b+1): A2 = bf16(K*q)
#pragma unroll
      for (int i2 = 0; i2 < 8; ++i2) {
        const float* qp = &qrowf[col0 + i2 * 4];
        bf16x4 h4 = {(__bf16)(kq[i2].x * qp[0]), (__bf16)(kq[i2].y * qp[1]),
                     (__bf16)(kq[i2].z * qp[2]), (__bf16)(kq[i2].w * qp[3])};
        *(bf16x4*)&A2[r * KSTR + col0 + i2 * 4] = h4;
      }
      __syncthreads();
    }
  }
}

extern "C" void kernel_launch(void* const* d_in, const int* in_sizes, int n_in,
                              void* d_out, int out_size, void* d_ws, size_t ws_size,
                              hipStream_t stream) {
  const int* qid_item = (const int*)d_in[0];
  const int* qid_cate = (const int*)d_in[1];
  const int* seq_item = (const int*)d_in[2];
  const int* seq_cate = (const int*)d_in[3];
  const int* mask     = (const int*)d_in[4];
  const float* emb_item = (const float*)d_in[5];
  const float* emb_cate = (const float*)d_in[6];
  const float* W_hide   = (const float*)d_in[7];
  const float* b_hide   = (const float*)d_in[8];
  const float* W_out    = (const float*)d_in[9];
  const float* b_out    = (const float*)d_in[10];
  float* out = (float*)d_out;

  (void)d_ws; (void)ws_size;  // intentionally unused

  prep_kernel<<<64, 256, 0, stream>>>(W_hide);
  din_main_kernel<<<4096 / NB, 256, 0, stream>>>(qid_item, qid_cate, seq_item,
                                                 seq_cate, mask, emb_item, emb_cate,
                                                 b_hide, W_out, b_out, out);
}

// Round 5
// 169.950 us; speedup vs baseline: 1.1535x; 1.1535x over previous
//
#include <hip/hip_runtime.h>
#include <hip/hip_bf16.h>

// Problem: B=4096, L=50, D=64, E=128, CAT=384, U=256, V=100000
// Dtypes per reference: ALL float tensors fp32, ids/mask int32, out fp32 [B,E].
//
// Factored algebra: h = relu(q·W_q + k·W_k + (q*k)·W_qk + b_hide)
//   qv[b][u] = b_hide[u] + q·W_q[:,u]  -> PRECOMPUTED for all b by qv_prep
//   (fp32 FMA, same summation order as before -> bit-identical numerics)
//   GEMM per b: swapped operands C[u,l]: A-op = W fragments (global, coalesced),
//   B-op = [K | K*q] rows (LDS).  C layout: col(lane&15)=l, row(quad*4+reg)=u.
// scores = (relu(C+qv)·W_out + b_out) * mask ; out[b] = scores · K   (fp32)
//
// History: V4 75.7us (W coalescing fix, 2x). V5 112us REGRESSION: intra-block
// pipeline cost 148 VGPR + grid/4 -> occupancy 11% -> reverted; lesson:
// block-level residency is the latency hider, don't spend registers on ILP.
// V6 = V4 + (a) qv hoisted to a batched prep kernel (removes 64 VMEM + 128
// VALU from the serial path, deletes one barrier + qv2 LDS), (b)
// __launch_bounds__(256,4): peak live regs ~110 after (a), cap 128 -> 4
// waves/SIMD -> 4 blocks/CU resident (vs 2.25).

#define L_SEQ 50
#define LP    64
#define D_EMB 64
#define E_DIM 128
#define U_DIM 256
#define CATK  384
#define V_SZ  100000
#define B_TOT 4096
#define KSTR  136   // LDS row stride (bf16): 272B = 17*16B -> bank rotation by 4/row

typedef __bf16 bf16x2 __attribute__((ext_vector_type(2)));
typedef __bf16 bf16x4 __attribute__((ext_vector_type(4)));
typedef __bf16 bf16x8 __attribute__((ext_vector_type(8)));
typedef float  f32x4  __attribute__((ext_vector_type(4)));

// module-owned caches (written each launch before main):
// g_W3: W_k/W_qk slice in MFMA fragment order: [s=8][ut=16][lane=64][j=8] bf16 =128KB
// g_QV: qv[b][u] = b_hide[u] + q_b·W_q[:,u], fp32, 4096x256 = 4MB
__device__ __bf16 g_W3[65536];
__device__ float  g_QV[B_TOT * U_DIM];

// ---- prep 1: g_W3 fragment shuffle ----
__global__ __launch_bounds__(256) void prep_kernel(const float* __restrict__ W_hide) {
  const int o = blockIdx.x * 256 + threadIdx.x;   // 0..8191
  const int s = o >> 10, ut = (o >> 6) & 15, lane = o & 63;
  const int quad = lane >> 4, m = lane & 15;
  const int u = ut * 16 + m;
  const int c0 = 128 + s * 32 + quad * 8;
  bf16x8 v;
#pragma unroll
  for (int j = 0; j < 8; ++j)
    v[j] = (__bf16)W_hide[(c0 + j) * 256 + u];  // scattered 4B reads (tiny kernel)
  *(bf16x8*)&g_W3[o * 8] = v;                   // coalesced 16B write
}

// ---- prep 2: g_QV[b][u] for all b. Summation order matches the old in-main
// qv phase exactly: acc0 = b_hide[u] + sum_{c=0..63} q[c]*bf16(W)[c][u] (asc),
// acc1 = sum_{c=64..127}, result = acc0 + acc1  -> bit-identical numerics. ----
__global__ __launch_bounds__(256) void qv_prep_kernel(
    const int* __restrict__ qid_item, const int* __restrict__ qid_cate,
    const float* __restrict__ emb_item, const float* __restrict__ emb_cate,
    const float* __restrict__ W_hide, const float* __restrict__ b_hide) {
  __shared__ float qs[16][E_DIM];        // 16 q rows, fp32 (8KB)
  __shared__ float qvp[2][16][U_DIM];    // per-c-half partials (32KB)
  const int b0 = blockIdx.x * 16;
  const int t = threadIdx.x;
  // gather 16 q rows: 512 float4 segments, 2 per thread
#pragma unroll
  for (int j = 0; j < 2; ++j) {
    const int idx = j * 256 + t;               // 0..511
    const int bs = idx >> 5, seg = idx & 31;   // b-sub, float4 segment
    int id = (seg < 16 ? qid_item : qid_cate)[b0 + bs];
    if ((unsigned)id >= (unsigned)V_SZ) id = 0;
    const float4* s4 = (const float4*)(((seg < 16) ? emb_item : emb_cate)
                                       + (size_t)id * D_EMB + (seg & 15) * 4);
    *(float4*)&qs[bs][(seg < 16 ? 0 : 64) + (seg & 15) * 4] = *s4;
  }
  __syncthreads();
  const int ch = t >> 7, u0 = (t & 127) * 2;   // c-half, owned u pair
  float a0[16], a1[16];
#pragma unroll
  for (int bs = 0; bs < 16; ++bs) {
    a0[bs] = ch ? 0.f : b_hide[u0];
    a1[bs] = ch ? 0.f : b_hide[u0 + 1];
  }
  const float* wrow = W_hide + (ch * 64) * 256 + u0;
  for (int cc = 0; cc < 64; ++cc) {
    const float w0 = (float)(__bf16)wrow[cc * 256];       // same bf16 rounding
    const float w1 = (float)(__bf16)wrow[cc * 256 + 1];
#pragma unroll
    for (int bs = 0; bs < 16; ++bs) {
      const float qc = qs[bs][ch * 64 + cc];
      a0[bs] += qc * w0;
      a1[bs] += qc * w1;
    }
  }
#pragma unroll
  for (int bs = 0; bs < 16; ++bs) {
    qvp[ch][bs][u0]     = a0[bs];
    qvp[ch][bs][u0 + 1] = a1[bs];
  }
  __syncthreads();
#pragma unroll
  for (int bs = 0; bs < 16; ++bs)
    g_QV[(size_t)(b0 + bs) * U_DIM + t] = qvp[0][bs][t] + qvp[1][bs][t];
}

// ---- main: one block (4 waves, 256 threads) per b ----
__global__ __launch_bounds__(256, 4) void din_main_kernel(
    const int* __restrict__ qid_item, const int* __restrict__ qid_cate,
    const int* __restrict__ seq_item, const int* __restrict__ seq_cate,
    const int* __restrict__ mask,
    const float* __restrict__ emb_item,
    const float* __restrict__ emb_cate,
    const float* __restrict__ W_out,   // [256]
    const float* __restrict__ b_out,   // [1]
    float* __restrict__ out) {
  __shared__ alignas(16) __bf16 Kb[LP * KSTR];   // bf16(K)
  __shared__ alignas(16) __bf16 A2[LP * KSTR];   // bf16(K*q)
  __shared__ alignas(16) float qrowf[E_DIM];     // fp32 q
  __shared__ float mask_f[LP];
  __shared__ float scpart[4][LP];                // per-wave u-partial scores
  __shared__ float scores_s[LP];
  __shared__ float outp[4][E_DIM];               // per-wave l-partial outputs

  const int b = blockIdx.x;
  const int t = threadIdx.x;
  const int r = t >> 2, q4 = t & 3;
  const int col0 = q4 * 32;   // this thread's 32 columns of [item|cate]

  // ---- phase 1: gather K rows (fp32) into regs, cast to LDS bf16 ----
  float4 kv[8];
  if (r < L_SEQ) {
    int id = (q4 < 2) ? seq_item[b * L_SEQ + r] : seq_cate[b * L_SEQ + r];
    if ((unsigned)id >= (unsigned)V_SZ) id = 0;   // insurance
    const float4* s4 = (const float4*)(((q4 < 2) ? emb_item : emb_cate)
                                       + (size_t)id * D_EMB + (q4 & 1) * 32);
#pragma unroll
    for (int i = 0; i < 8; ++i) kv[i] = s4[i];
  } else {
#pragma unroll
    for (int i = 0; i < 8; ++i) kv[i] = make_float4(0.f, 0.f, 0.f, 0.f);
  }
#pragma unroll
  for (int i = 0; i < 8; ++i) {
    bf16x4 h4 = {(__bf16)kv[i].x, (__bf16)kv[i].y, (__bf16)kv[i].z, (__bf16)kv[i].w};
    *(bf16x4*)&Kb[r * KSTR + col0 + i * 4] = h4;   // 8B store, aligned
  }
  if (t < 4) {   // q row: 4 threads x 32 floats
    int id = (t < 2) ? qid_item[b] : qid_cate[b];
    if ((unsigned)id >= (unsigned)V_SZ) id = 0;
    const float4* s4 = (const float4*)(((t < 2) ? emb_item : emb_cate)
                                       + (size_t)id * D_EMB + (t & 1) * 32);
    float4* d4 = (float4*)&qrowf[t * 32];
#pragma unroll
    for (int i = 0; i < 8; ++i) d4[i] = s4[i];
  }
  if (t < LP) mask_f[t] = (t < L_SEQ && mask[b * L_SEQ + t] != 0) ? 1.0f : 0.0f;
  __syncthreads();

  // ---- phase 2: A2 = bf16(K * q) from fp32 regs (single rounding) ----
#pragma unroll
  for (int i = 0; i < 8; ++i) {
    const float* qp = &qrowf[col0 + i * 4];
    bf16x4 h4 = {(__bf16)(kv[i].x * qp[0]), (__bf16)(kv[i].y * qp[1]),
                 (__bf16)(kv[i].z * qp[2]), (__bf16)(kv[i].w * qp[3])};
    *(bf16x4*)&A2[r * KSTR + col0 + i * 4] = h4;
  }
  __syncthreads();

  // ---- phase 3: swapped MFMA. M=u (64/wave, 4 tiles), N=l (64, 4 tiles),
  //      K=256 (8 steps). A-op = g_W3 fragments (coalesced), B-op = Kb/A2 (LDS).
  const int wave = t >> 6, lane = t & 63;
  const int m = lane & 15, quad = lane >> 4;
  f32x4 acc[4][4];
#pragma unroll
  for (int mt = 0; mt < 4; ++mt)
#pragma unroll
    for (int nt = 0; nt < 4; ++nt) acc[mt][nt] = (f32x4){0.f, 0.f, 0.f, 0.f};

#pragma unroll
  for (int s = 0; s < 8; ++s) {
    const __bf16* Bb = (s < 4) ? Kb : A2;
    const int klocal = (s & 3) * 32 + quad * 8;
    bf16x8 wfr[4], kfr[4];
#pragma unroll
    for (int mt = 0; mt < 4; ++mt) {
      const int o = s * 1024 + (wave * 4 + mt) * 64 + lane;   // fragment-ordered
      wfr[mt] = *(const bf16x8*)&g_W3[o * 8];
    }
#pragma unroll
    for (int nt = 0; nt < 4; ++nt)
      kfr[nt] = *(const bf16x8*)&Bb[(nt * 16 + m) * KSTR + klocal];
#pragma unroll
    for (int mt = 0; mt < 4; ++mt)
#pragma unroll
      for (int nt = 0; nt < 4; ++nt)
        acc[mt][nt] = __builtin_amdgcn_mfma_f32_16x16x32_bf16(
            wfr[mt], kfr[nt], acc[mt][nt], 0, 0, 0);
  }
  // no barrier needed: epilogue reads only private acc + global g_QV/W_out

  // ---- epilogue: C[u,l]: u = wave*64+mt*16+quad*4+rg (in-lane), l = nt*16+m.
  //      part[nt] = sum_u relu(C+qv[u])*W_out[u]  — u-reduce is in-lane + quads.
  float qv4[4][4], wo4[4][4];
#pragma unroll
  for (int mt = 0; mt < 4; ++mt) {
    const int u0 = wave * 64 + mt * 16 + quad * 4;
    f32x4 qq = *(const f32x4*)&g_QV[(size_t)b * U_DIM + u0];  // precomputed qv
    float4 ww = *(const float4*)&W_out[u0];
    qv4[mt][0] = qq[0]; qv4[mt][1] = qq[1]; qv4[mt][2] = qq[2]; qv4[mt][3] = qq[3];
    wo4[mt][0] = ww.x;  wo4[mt][1] = ww.y;  wo4[mt][2] = ww.z;  wo4[mt][3] = ww.w;
  }
  float part[4];
#pragma unroll
  for (int nt = 0; nt < 4; ++nt) {
    float sum = 0.f;
#pragma unroll
    for (int mt = 0; mt < 4; ++mt)
#pragma unroll
      for (int rg = 0; rg < 4; ++rg) {
        float h = acc[mt][nt][rg] + qv4[mt][rg];
        h = fmaxf(h, 0.f);
        sum += h * wo4[mt][rg];
      }
    part[nt] = sum;
  }
#pragma unroll
  for (int nt = 0; nt < 4; ++nt) {   // reduce over 4 quads
    part[nt] += __shfl_xor(part[nt], 16, 64);
    part[nt] += __shfl_xor(part[nt], 32, 64);
  }
  if (lane < 16) {
#pragma unroll
    for (int nt = 0; nt < 4; ++nt)
      scpart[wave][nt * 16 + lane] = part[nt];   // l = nt*16+lane
  }
  __syncthreads();

  // ---- scores (t<64), then wave-parallel out partials ----
  if (t < LP) {
    float s = scpart[0][t] + scpart[1][t] + scpart[2][t] + scpart[3][t]
            + b_out[0];
    scores_s[t] = s * mask_f[t];
  }
  __syncthreads();
  // wave w accumulates rows [w*16, w*16+16); lane covers e = 2*lane, 2*lane+1
  {
    const int e2 = lane * 2;
    float o0 = 0.f, o1 = 0.f;
#pragma unroll
    for (int i = 0; i < 16; ++i) {
      const int l = wave * 16 + i;
      const float sc = scores_s[l];                       // broadcast
      bf16x2 kk = *(const bf16x2*)&Kb[l * KSTR + e2];     // b32 pair, 2-way banks
      o0 += sc * (float)kk[0];
      o1 += sc * (float)kk[1];
    }
    outp[wave][e2]     = o0;
    outp[wave][e2 + 1] = o1;
  }
  __syncthreads();
  if (t < E_DIM) {
    float o = outp[0][t] + outp[1][t] + outp[2][t] + outp[3][t];
    out[(size_t)b * E_DIM + t] = o;
  }
}

extern "C" void kernel_launch(void* const* d_in, const int* in_sizes, int n_in,
                              void* d_out, int out_size, void* d_ws, size_t ws_size,
                              hipStream_t stream) {
  const int* qid_item = (const int*)d_in[0];
  const int* qid_cate = (const int*)d_in[1];
  const int* seq_item = (const int*)d_in[2];
  const int* seq_cate = (const int*)d_in[3];
  const int* mask     = (const int*)d_in[4];
  const float* emb_item = (const float*)d_in[5];
  const float* emb_cate = (const float*)d_in[6];
  const float* W_hide   = (const float*)d_in[7];
  const float* b_hide   = (const float*)d_in[8];
  const float* W_out    = (const float*)d_in[9];
  const float* b_out    = (const float*)d_in[10];
  float* out = (float*)d_out;

  (void)d_ws; (void)ws_size;  // intentionally unused

  prep_kernel<<<32, 256, 0, stream>>>(W_hide);
  qv_prep_kernel<<<B_TOT / 16, 256, 0, stream>>>(qid_item, qid_cate,
                                                 emb_item, emb_cate,
                                                 W_hide, b_hide);
  din_main_kernel<<<B_TOT, 256, 0, stream>>>(qid_item, qid_cate, seq_item,
                                             seq_cate, mask, emb_item, emb_cate,
                                             W_out, b_out, out);
}

// Round 7
// 156.346 us; speedup vs baseline: 1.2538x; 1.0870x over previous
//
#include <hip/hip_runtime.h>
#include <hip/hip_bf16.h>

// Problem: B=4096, L=50, D=64, E=128, CAT=384, U=256, V=100000
// Dtypes per reference: ALL float tensors fp32, ids/mask int32, out fp32 [B,E].
//
// Factored algebra: h = relu(q·W_q + k·W_k + (q*k)·W_qk + b_hide)
//   GEMM per b (swapped operands) C[u,l]: A-op = W fragments (global, coalesced),
//   B-op = [K | K*q] rows (LDS). C layout: col(lane&15)=l, row(quad*4+reg)=u.
//   qv[u] = b_hide[u] + q·W_q[:,u]: computed IN-KERNEL via one extra N=16 MFMA
//   tile (4 K-steps): B-row 0 = bf16(q) planted in Kb padding row 50 (masked),
//   rows 51..65 = in-bounds garbage (their C-columns are discarded); only the
//   m==0 lanes' column-0 results are kept -> qv_s LDS.
// scores = (relu(C+qv)·W_out + b_out) * mask ; out[b] = scores · K   (fp32)
//
// History: V4 75.7us (W fragment coalescing, the 2x lever). V5 112us REGRESSION
// (intra-block pipeline destroyed residency). V6 62.6us main (qv hoisted to a
// prep kernel, 4 blocks/CU) BUT the prep cost 22us + 21MB cross-XCD g_QV
// traffic -> total regressed. V7 folds qv into main's MFMA pipe (idle at 21%):
// +16 MFMA/wave, zero extra B-operand LDS, no prep-qv kernel, no g_QV.
// NUMERICS: qv now bf16-in/fp32-acc MFMA (was fp32 FMA) -> absmax shifts.
// R6: bench infra failed ("container failed twice") — audited for crash
// vectors (LDS bounds, garbage-row NaN, races, harness rules): none found.
// Resubmitting unchanged.

#define L_SEQ 50
#define LP    64
#define D_EMB 64
#define E_DIM 128
#define U_DIM 256
#define CATK  384
#define V_SZ  100000
#define B_TOT 4096
#define KSTR  136   // LDS row stride (bf16): 272B = 17*16B -> bank rotation by 4/row

typedef __bf16 bf16x2 __attribute__((ext_vector_type(2)));
typedef __bf16 bf16x4 __attribute__((ext_vector_type(4)));
typedef __bf16 bf16x8 __attribute__((ext_vector_type(8)));
typedef float  f32x4  __attribute__((ext_vector_type(4)));

// module-owned: g_W3 = ALL of W_hide in MFMA fragment order, 12 K-slices:
// g_W3[((s*16+ut)*64+lane)*8+j] = bf16(W_hide[(s*32 + (lane>>4)*8 + j)*256
//                                            + ut*16 + (lane&15)])
// s=0..3 -> W_q (c 0..127), s=4..7 -> W_k, s=8..11 -> W_qk.  192 KB.
__device__ __bf16 g_W3[12288 * 8];

// ---- prep: g_W3 fragment shuffle (48 blocks x 256 thr, one fragment/thread) ----
__global__ __launch_bounds__(256) void prep_kernel(const float* __restrict__ W_hide) {
  const int o = blockIdx.x * 256 + threadIdx.x;   // 0..12287
  const int s = o >> 10, ut = (o >> 6) & 15, lane = o & 63;
  const int quad = lane >> 4, m = lane & 15;
  const int u = ut * 16 + m;
  const int c0 = s * 32 + quad * 8;
  bf16x8 v;
#pragma unroll
  for (int j = 0; j < 8; ++j)
    v[j] = (__bf16)W_hide[(c0 + j) * 256 + u];  // scattered 4B reads (tiny kernel)
  *(bf16x8*)&g_W3[o * 8] = v;                   // coalesced 16B write
}

// ---- main: one block (4 waves, 256 threads) per b ----
__global__ __launch_bounds__(256, 4) void din_main_kernel(
    const int* __restrict__ qid_item, const int* __restrict__ qid_cate,
    const int* __restrict__ seq_item, const int* __restrict__ seq_cate,
    const int* __restrict__ mask,
    const float* __restrict__ emb_item,
    const float* __restrict__ emb_cate,
    const float* __restrict__ b_hide,  // [256]
    const float* __restrict__ W_out,   // [256]
    const float* __restrict__ b_out,   // [1]
    float* __restrict__ out) {
  // Kb and A2 CONTIGUOUS: qv B-fragment reads rows 50..65 of the combined array.
  __shared__ alignas(16) __bf16 KbA2[2 * LP * KSTR];   // 34816 B
  __shared__ alignas(16) float qrowf[E_DIM];           // fp32 q
  __shared__ alignas(16) float qv_s[U_DIM];            // b_hide + q·W_q (from MFMA)
  __shared__ float mask_f[LP];
  __shared__ float scpart[4][LP];                      // per-wave u-partial scores
  __shared__ float scores_s[LP];
  __shared__ float outp[4][E_DIM];                     // per-wave l-partial outputs
  __bf16* const Kb = KbA2;
  __bf16* const A2 = KbA2 + LP * KSTR;

  const int b = blockIdx.x;
  const int t = threadIdx.x;
  const int r = t >> 2, q4 = t & 3;
  const int col0 = q4 * 32;   // this thread's 32 columns of [item|cate]
  const int wave = t >> 6, lane = t & 63;
  const int m = lane & 15, quad = lane >> 4;

  // ---- phase 1: gather K rows (fp32) into regs, cast to LDS bf16 ----
  float4 kv[8];
  if (r < L_SEQ) {
    int id = (q4 < 2) ? seq_item[b * L_SEQ + r] : seq_cate[b * L_SEQ + r];
    if ((unsigned)id >= (unsigned)V_SZ) id = 0;   // insurance
    const float4* s4 = (const float4*)(((q4 < 2) ? emb_item : emb_cate)
                                       + (size_t)id * D_EMB + (q4 & 1) * 32);
#pragma unroll
    for (int i = 0; i < 8; ++i) kv[i] = s4[i];
  } else {
#pragma unroll
    for (int i = 0; i < 8; ++i) kv[i] = make_float4(0.f, 0.f, 0.f, 0.f);
  }
#pragma unroll
  for (int i = 0; i < 8; ++i) {
    bf16x4 h4 = {(__bf16)kv[i].x, (__bf16)kv[i].y, (__bf16)kv[i].z, (__bf16)kv[i].w};
    *(bf16x4*)&Kb[r * KSTR + col0 + i * 4] = h4;   // 8B store, aligned
  }
  if (t < 4) {   // q row: 4 threads x 32 floats
    int id = (t < 2) ? qid_item[b] : qid_cate[b];
    if ((unsigned)id >= (unsigned)V_SZ) id = 0;
    const float4* s4 = (const float4*)(((t < 2) ? emb_item : emb_cate)
                                       + (size_t)id * D_EMB + (t & 1) * 32);
    float4* d4 = (float4*)&qrowf[t * 32];
#pragma unroll
    for (int i = 0; i < 8; ++i) d4[i] = s4[i];
  }
  if (t < LP) mask_f[t] = (t < L_SEQ && mask[b * L_SEQ + t] != 0) ? 1.0f : 0.0f;
  __syncthreads();

  // ---- phase 2: A2 = bf16(K * q) from fp32 regs (single rounding);
  //      plant bf16(q) into Kb padding row 50 (masked row -> harmless) ----
#pragma unroll
  for (int i = 0; i < 8; ++i) {
    const float* qp = &qrowf[col0 + i * 4];
    bf16x4 h4 = {(__bf16)(kv[i].x * qp[0]), (__bf16)(kv[i].y * qp[1]),
                 (__bf16)(kv[i].z * qp[2]), (__bf16)(kv[i].w * qp[3])};
    *(bf16x4*)&A2[r * KSTR + col0 + i * 4] = h4;
  }
  if (r == 50) {
#pragma unroll
    for (int i = 0; i < 8; ++i) {
      const float* qp = &qrowf[col0 + i * 4];
      bf16x4 h4 = {(__bf16)qp[0], (__bf16)qp[1], (__bf16)qp[2], (__bf16)qp[3]};
      *(bf16x4*)&Kb[50 * KSTR + col0 + i * 4] = h4;
    }
  }
  __syncthreads();

  // ---- phase 3a: qv via MFMA. One N=16 tile, K=128 (slices 0..3 = W_q).
  //      B rows = KbA2 rows 50..65: row 50 = q, rest garbage (cols discarded).
  {
    f32x4 acc2[4];
#pragma unroll
    for (int mt = 0; mt < 4; ++mt) acc2[mt] = (f32x4){0.f, 0.f, 0.f, 0.f};
#pragma unroll
    for (int s = 0; s < 4; ++s) {
      const int klocal = s * 32 + quad * 8;
      bf16x8 kq = *(const bf16x8*)&KbA2[(50 + m) * KSTR + klocal];
      bf16x8 wq[4];
#pragma unroll
      for (int mt = 0; mt < 4; ++mt)
        wq[mt] = *(const bf16x8*)&g_W3[(s * 1024 + (wave * 4 + mt) * 64 + lane) * 8];
#pragma unroll
      for (int mt = 0; mt < 4; ++mt)
        acc2[mt] = __builtin_amdgcn_mfma_f32_16x16x32_bf16(wq[mt], kq, acc2[mt],
                                                           0, 0, 0);
    }
    if (m == 0) {   // only column 0 (B-row 50 = q) is the true qv
#pragma unroll
      for (int mt = 0; mt < 4; ++mt) {
        const int u0 = wave * 64 + mt * 16 + quad * 4;
        float4 bh = *(const float4*)&b_hide[u0];
        f32x4 v = acc2[mt];
        v[0] += bh.x; v[1] += bh.y; v[2] += bh.z; v[3] += bh.w;
        *(f32x4*)&qv_s[u0] = v;
      }
    }
  }
  __syncthreads();   // qv_s visible to all epilogue readers

  // ---- phase 3b: main MFMA. M=u (64/wave, 4 tiles), N=l (64, 4 tiles),
  //      K=256 (slices 4..11). A-op = g_W3 fragments, B-op = Kb/A2 (LDS). ----
  f32x4 acc[4][4];
#pragma unroll
  for (int mt = 0; mt < 4; ++mt)
#pragma unroll
    for (int nt = 0; nt < 4; ++nt) acc[mt][nt] = (f32x4){0.f, 0.f, 0.f, 0.f};

#pragma unroll
  for (int s = 0; s < 8; ++s) {
    const __bf16* Bb = (s < 4) ? Kb : A2;
    const int klocal = (s & 3) * 32 + quad * 8;
    bf16x8 wfr[4], kfr[4];
#pragma unroll
    for (int mt = 0; mt < 4; ++mt) {
      const int o = (4 + s) * 1024 + (wave * 4 + mt) * 64 + lane;  // frag-ordered
      wfr[mt] = *(const bf16x8*)&g_W3[o * 8];
    }
#pragma unroll
    for (int nt = 0; nt < 4; ++nt)
      kfr[nt] = *(const bf16x8*)&Bb[(nt * 16 + m) * KSTR + klocal];
#pragma unroll
    for (int mt = 0; mt < 4; ++mt)
#pragma unroll
      for (int nt = 0; nt < 4; ++nt)
        acc[mt][nt] = __builtin_amdgcn_mfma_f32_16x16x32_bf16(
            wfr[mt], kfr[nt], acc[mt][nt], 0, 0, 0);
  }
  // no barrier needed: epilogue reads private acc + qv_s (sync'd above) + W_out

  // ---- epilogue: C[u,l]: u = wave*64+mt*16+quad*4+rg (in-lane), l = nt*16+m.
  //      part[nt] = sum_u relu(C+qv[u])*W_out[u]  — u-reduce in-lane + quads.
  float qv4[4][4], wo4[4][4];
#pragma unroll
  for (int mt = 0; mt < 4; ++mt) {
    const int u0 = wave * 64 + mt * 16 + quad * 4;
    f32x4 qq = *(const f32x4*)&qv_s[u0];        // LDS broadcast per 16 lanes
    float4 ww = *(const float4*)&W_out[u0];
    qv4[mt][0] = qq[0]; qv4[mt][1] = qq[1]; qv4[mt][2] = qq[2]; qv4[mt][3] = qq[3];
    wo4[mt][0] = ww.x;  wo4[mt][1] = ww.y;  wo4[mt][2] = ww.z;  wo4[mt][3] = ww.w;
  }
  float part[4];
#pragma unroll
  for (int nt = 0; nt < 4; ++nt) {
    float sum = 0.f;
#pragma unroll
    for (int mt = 0; mt < 4; ++mt)
#pragma unroll
      for (int rg = 0; rg < 4; ++rg) {
        float h = acc[mt][nt][rg] + qv4[mt][rg];
        h = fmaxf(h, 0.f);
        sum += h * wo4[mt][rg];
      }
    part[nt] = sum;
  }
#pragma unroll
  for (int nt = 0; nt < 4; ++nt) {   // reduce over 4 quads
    part[nt] += __shfl_xor(part[nt], 16, 64);
    part[nt] += __shfl_xor(part[nt], 32, 64);
  }
  if (lane < 16) {
#pragma unroll
    for (int nt = 0; nt < 4; ++nt)
      scpart[wave][nt * 16 + lane] = part[nt];   // l = nt*16+lane
  }
  __syncthreads();

  // ---- scores (t<64), then wave-parallel out partials ----
  if (t < LP) {
    float s = scpart[0][t] + scpart[1][t] + scpart[2][t] + scpart[3][t]
            + b_out[0];
    scores_s[t] = s * mask_f[t];
  }
  __syncthreads();
  // wave w accumulates rows [w*16, w*16+16); lane covers e = 2*lane, 2*lane+1
  {
    const int e2 = lane * 2;
    float o0 = 0.f, o1 = 0.f;
#pragma unroll
    for (int i = 0; i < 16; ++i) {
      const int l = wave * 16 + i;
      const float sc = scores_s[l];                       // broadcast
      bf16x2 kk = *(const bf16x2*)&Kb[l * KSTR + e2];     // b32 pair, 2-way banks
      o0 += sc * (float)kk[0];
      o1 += sc * (float)kk[1];
    }
    outp[wave][e2]     = o0;
    outp[wave][e2 + 1] = o1;
  }
  __syncthreads();
  if (t < E_DIM) {
    float o = outp[0][t] + outp[1][t] + outp[2][t] + outp[3][t];
    out[(size_t)b * E_DIM + t] = o;
  }
}

extern "C" void kernel_launch(void* const* d_in, const int* in_sizes, int n_in,
                              void* d_out, int out_size, void* d_ws, size_t ws_size,
                              hipStream_t stream) {
  const int* qid_item = (const int*)d_in[0];
  const int* qid_cate = (const int*)d_in[1];
  const int* seq_item = (const int*)d_in[2];
  const int* seq_cate = (const int*)d_in[3];
  const int* mask     = (const int*)d_in[4];
  const float* emb_item = (const float*)d_in[5];
  const float* emb_cate = (const float*)d_in[6];
  const float* W_hide   = (const float*)d_in[7];
  const float* b_hide   = (const float*)d_in[8];
  const float* W_out    = (const float*)d_in[9];
  const float* b_out    = (const float*)d_in[10];
  float* out = (float*)d_out;

  (void)d_ws; (void)ws_size;  // intentionally unused

  prep_kernel<<<48, 256, 0, stream>>>(W_hide);
  din_main_kernel<<<B_TOT, 256, 0, stream>>>(qid_item, qid_cate, seq_item,
                                             seq_cate, mask, emb_item, emb_cate,
                                             b_hide, W_out, b_out, out);
}